// Round 9
// baseline (865.991 us; speedup 1.0000x reference)
//
#include <hip/hip_runtime.h>
#include <math.h>

#define N_NODES 50000
#define IN_CH   128
#define HEADS   4
#define HID     64
#define NEDGE   800000
#define EPS     1e-6f
#define LN_EPS  1e-5f
#define NCHUNK  49            // ceil(N_NODES / 1024)

// ---- cross-lane reduce helpers --------------------------------------
#define DPP_ADD_F(p, ctrl) \
    p += __int_as_float(__builtin_amdgcn_update_dpp(0, __float_as_int(p), ctrl, 0xF, 0xF, true))
// 16-lane butterfly: xor {1,2,7,15}
#define REDUCE16_DPP(p) { DPP_ADD_F(p,0xB1); DPP_ADD_F(p,0x4E); \
                          DPP_ADD_F(p,0x141); DPP_ADD_F(p,0x140); }
#define REDUCE16(p) { p += __shfl_xor(p,1); p += __shfl_xor(p,2); \
                      p += __shfl_xor(p,4); p += __shfl_xor(p,8); }
#define REDUCE64(p) { REDUCE16_DPP(p); p += __shfl_xor(p,16); p += __shfl_xor(p,32); }
#define REDUCE64I(p) { p += __shfl_xor(p,1); p += __shfl_xor(p,2); \
                       p += __shfl_xor(p,4); p += __shfl_xor(p,8); \
                       p += __shfl_xor(p,16); p += __shfl_xor(p,32); }

// ---- grid-wide sync: all gridDim.x blocks are co-resident by construction
// (grid <= #CUs, 1 block/CU fits: LDS 55KB, <=16 waves, VGPR<=128).
// __threadfence() on gfx950 = seq_cst agent fence (L2 writeback + inv),
// making cross-XCD writes visible despite non-coherent per-XCD L2s.
__device__ __forceinline__ void grid_sync(int* cnt, int target) {
    __threadfence();
    __syncthreads();
    if (threadIdx.x == 0) {
        __hip_atomic_fetch_add(cnt, 1, __ATOMIC_ACQ_REL, __HIP_MEMORY_SCOPE_AGENT);
        while (__hip_atomic_load(cnt, __ATOMIC_ACQUIRE, __HIP_MEMORY_SCOPE_AGENT) < target)
            __builtin_amdgcn_s_sleep(2);
    }
    __syncthreads();
    __threadfence();
}

// ---------------- the mega-kernel ------------------------------------
// Phase H: edge histogram (fire-and-forget atomics) + h = x @ lin_w.T
// SYNC0 -> P0: per-1024-chunk partial sums
// SYNC1 -> P1: chunk-base + block scan -> offsets, cursor
// SYNC2 -> P2: CSR fill
// SYNC3 -> P3: per-node gather (ILP-16) + bcos linear + layernorm
__global__ __launch_bounds__(1024, 4) void mega_kernel(
        const float* __restrict__ x, const int* __restrict__ ei,
        const float* __restrict__ lin_w, const float* __restrict__ bcos_w,
        const float* __restrict__ gamma, const float* __restrict__ beta,
        float* __restrict__ y,
        float* __restrict__ h, float* __restrict__ inv_hn,
        int* __restrict__ deg, int* cnt, int* __restrict__ partial,
        int* __restrict__ offsets, int* __restrict__ cursor,
        int* __restrict__ csr_col) {
    __shared__ float4 wt[32 * 65];        // GEMM weights [k4][c], 33.3 KB
    __shared__ float4 wt4[16][65];        // bcos weights [k4][j], 16.6 KB
    __shared__ float  rowbuf[16][HID];    // 4 KB (per-wave row)
    __shared__ float  ivw[HID], gm[HID], bt[HID];
    __shared__ int    wsum[16];
    __shared__ int    bbase_s;

    const int nblk   = gridDim.x;
    const int tid    = threadIdx.x;
    const int lane   = tid & 63;
    const int wv     = tid >> 6;          // wave id 0..15
    const int head   = lane >> 4;
    const int gwave  = blockIdx.x * 16 + wv;
    const int nwaves = nblk * 16;

    // ---- stage LDS constants ----
    for (int i = tid; i < HID * (IN_CH / 4); i += 1024) {
        int c = i >> 5, k4 = i & 31;
        wt[k4 * 65 + c] = ((const float4*)lin_w)[i];
    }
    {
        int i = tid;
        if (i < HID * (HID / 4)) {        // exactly 1024
            int j = i >> 4, k4 = i & 15;
            wt4[k4][j] = ((const float4*)bcos_w)[i];
        }
    }
    if (tid < HID) {
        gm[tid] = gamma[tid];
        bt[tid] = beta[tid];
        const float4* w4 = (const float4*)bcos_w;
        float ss = 0.f;
#pragma unroll
        for (int k4 = 0; k4 < HID / 4; ++k4) {
            float4 q = w4[tid * (HID / 4) + k4];
            ss += q.x * q.x + q.y * q.y + q.z * q.z + q.w * q.w;
        }
        ivw[tid] = 1.0f / fmaxf(sqrtf(ss), 1e-12f);
    }

    // ---- phase H1: histogram (atomics retire under GEMM) ----
    for (int t = blockIdx.x * 1024 + tid; t < NEDGE / 4; t += nblk * 1024) {
        int4 r = ((const int4*)ei)[t];
        atomicAdd(&deg[r.x], 1);
        atomicAdd(&deg[r.y], 1);
        atomicAdd(&deg[r.z], 1);
        atomicAdd(&deg[r.w], 1);
    }
    __syncthreads();                      // wt ready

    // ---- phase H2: h = x @ lin_w.T + per-head inv norms ----
    const float4* xp = (const float4*)x;
    for (int g = gwave; g < N_NODES / 4; g += nwaves) {
        int n0 = __builtin_amdgcn_readfirstlane(g * 4);
        float a0 = 0.f, a1 = 0.f, a2 = 0.f, a3 = 0.f;
#pragma unroll 2
        for (int k4 = 0; k4 < IN_CH / 4; ++k4) {
            float4 wv4 = wt[k4 * 65 + lane];
            float4 x0 = xp[(n0 + 0) * 32 + k4];   // uniform -> s_load
            float4 x1 = xp[(n0 + 1) * 32 + k4];
            float4 x2 = xp[(n0 + 2) * 32 + k4];
            float4 x3 = xp[(n0 + 3) * 32 + k4];
            a0 += wv4.x * x0.x + wv4.y * x0.y + wv4.z * x0.z + wv4.w * x0.w;
            a1 += wv4.x * x1.x + wv4.y * x1.y + wv4.z * x1.z + wv4.w * x1.w;
            a2 += wv4.x * x2.x + wv4.y * x2.y + wv4.z * x2.z + wv4.w * x2.w;
            a3 += wv4.x * x3.x + wv4.y * x3.y + wv4.z * x3.z + wv4.w * x3.w;
        }
        float accs[4] = {a0, a1, a2, a3};
#pragma unroll
        for (int j = 0; j < 4; ++j) {
            int node = n0 + j;
            h[node * HID + lane] = accs[j];
            float ss = accs[j] * accs[j];
            REDUCE16_DPP(ss);
            if ((lane & 15) == 0)
                inv_hn[node * HEADS + (lane >> 4)] = 1.0f / fmaxf(sqrtf(ss), 1e-12f);
        }
    }

    grid_sync(&cnt[0], nblk);

    // ---- P0: per-chunk partial sums ----
    if (blockIdx.x < NCHUNK) {
        int i = blockIdx.x * 1024 + tid;
        int v = (i < N_NODES) ? deg[i] : 0;
        REDUCE64I(v);
        if (lane == 0) wsum[wv] = v;
        __syncthreads();
        if (wv == 0) {
            int t2 = (lane < 16) ? wsum[lane] : 0;
            REDUCE16(t2);
            if (lane == 0) partial[blockIdx.x] = t2;
        }
    }

    grid_sync(&cnt[1], nblk);

    // ---- P1: offsets/cursor scan ----
    if (blockIdx.x < NCHUNK) {
        int b = blockIdx.x;
        if (tid < 64) {
            int v = (lane < b) ? partial[lane] : 0;
            REDUCE64I(v);
            if (lane == 0) bbase_s = v;
        }
        int i = b * 1024 + tid;
        int val = (i < N_NODES) ? deg[i] : 0;
        int s = val;
#pragma unroll
        for (int off = 1; off < 64; off <<= 1) {
            int t2 = __shfl_up(s, off);
            if (lane >= off) s += t2;
        }
        if (lane == 63) wsum[wv] = s;
        __syncthreads();
        if (wv == 0 && lane < 16) {
            int t2 = wsum[lane];
#pragma unroll
            for (int off = 1; off < 16; off <<= 1) {
                int u = __shfl_up(t2, off);
                if (lane >= off) t2 += u;
            }
            wsum[lane] = t2;
        }
        __syncthreads();
        int incl = bbase_s + ((wv == 0) ? 0 : wsum[wv - 1]) + s;
        if (i < N_NODES) {
            offsets[i] = incl - val;
            cursor[i]  = incl - val;
        }
        if (b == NCHUNK - 1 && tid == 1023) offsets[N_NODES] = incl;
    }

    grid_sync(&cnt[2], nblk);

    // ---- P2: CSR fill ----
    for (int t = blockIdx.x * 1024 + tid; t < NEDGE / 4; t += nblk * 1024) {
        int4 r = ((const int4*)ei)[t];
        int4 c = ((const int4*)(ei + NEDGE))[t];
        csr_col[atomicAdd(&cursor[r.x], 1)] = c.x;
        csr_col[atomicAdd(&cursor[r.y], 1)] = c.y;
        csr_col[atomicAdd(&cursor[r.z], 1)] = c.z;
        csr_col[atomicAdd(&cursor[r.w], 1)] = c.w;
    }

    grid_sync(&cnt[3], nblk);

    // ---- P3: gather (ILP-16) + bcos linear + layernorm ----
    for (int node = gwave; node < N_NODES; node += nwaves) {
        float hr  = h[node * HID + lane];
        float ihr = inv_hn[node * HEADS + head];
        float hrs = hr * ihr;
        int start = __builtin_amdgcn_readfirstlane(offsets[node]);
        int end   = __builtin_amdgcn_readfirstlane(offsets[node + 1]);

        float ac0 = 0.f, ac1 = 0.f, ac2 = 0.f, ac3 = 0.f;
        int b = start;
#pragma unroll 1
        for (; b + 16 <= end; b += 16) {
            int cc[16];
#pragma unroll
            for (int j = 0; j < 16; ++j) cc[j] = csr_col[b + j];      // s_loads
            float hh[16];
#pragma unroll
            for (int j = 0; j < 16; ++j) hh[j] = h[cc[j] * HID + lane];
            float ii[16];
#pragma unroll
            for (int j = 0; j < 16; ++j) ii[j] = inv_hn[cc[j] * HEADS + head];
#pragma unroll
            for (int j = 0; j < 16; ++j) {
                float p = hh[j] * hrs;
                REDUCE16_DPP(p);
                float s = fminf(fmaxf(p * ii[j], EPS), 1.0f);   // B_EXP=2
                if ((j & 3) == 0)      ac0 = fmaf(hh[j], s, ac0);
                else if ((j & 3) == 1) ac1 = fmaf(hh[j], s, ac1);
                else if ((j & 3) == 2) ac2 = fmaf(hh[j], s, ac2);
                else                   ac3 = fmaf(hh[j], s, ac3);
            }
        }
        int rem = end - b;
        if (rem > 0) {                       // masked 16-wide tail (uniform idx)
            int cc[16];
#pragma unroll
            for (int j = 0; j < 16; ++j) cc[j] = csr_col[b + ((j < rem) ? j : rem - 1)];
            float hh[16];
#pragma unroll
            for (int j = 0; j < 16; ++j) hh[j] = h[cc[j] * HID + lane];
            float ii[16];
#pragma unroll
            for (int j = 0; j < 16; ++j) ii[j] = inv_hn[cc[j] * HEADS + head];
#pragma unroll
            for (int j = 0; j < 16; ++j) {
                float p = hh[j] * hrs;
                REDUCE16_DPP(p);
                float s = fminf(fmaxf(p * ii[j], EPS), 1.0f);
                s = (j < rem) ? s : 0.0f;
                if (j & 1) ac1 = fmaf(hh[j], s, ac1);
                else       ac0 = fmaf(hh[j], s, ac0);
            }
        }
        float acc = (ac0 + ac1) + (ac2 + ac3);

        // ---- fused epilogue: bcos linear + layernorm ----
        rowbuf[wv][lane] = acc;              // wave-private
        float ss = acc * acc;
        REDUCE64(ss);
        float inv_no = 1.0f / fmaxf(sqrtf(ss), 1e-12f);

        const float4* rb4 = (const float4*)rowbuf[wv];
        float lin = 0.f;
#pragma unroll
        for (int k4 = 0; k4 < 16; ++k4) {
            float4 a  = rb4[k4];             // broadcast read
            float4 wv4 = wt4[k4][lane];      // contiguous b128
            lin += a.x * wv4.x + a.y * wv4.y + a.z * wv4.z + a.w * wv4.w;
        }

        float c2v = lin * inv_no * ivw[lane];
        c2v = fminf(fmaxf(c2v, EPS), 1.0f);
        float ob = lin * c2v;                // B_EXP=2 -> cos2**1

        float mu = ob;
        REDUCE64(mu);
        mu *= (1.0f / 64.0f);
        float d = ob - mu;
        float var = d * d;
        REDUCE64(var);
        var *= (1.0f / 64.0f);
        float r = rsqrtf(var + LN_EPS);
        y[node * HID + lane] = d * r * gm[lane] + bt[lane];
    }
}

// ---------------------------------------------------------------------
extern "C" void kernel_launch(void* const* d_in, const int* in_sizes, int n_in,
                              void* d_out, int out_size, void* d_ws, size_t ws_size,
                              hipStream_t stream) {
    const float* x      = (const float*)d_in[0];
    const int*   ei     = (const int*)d_in[1];
    const float* lin_w  = (const float*)d_in[2];
    const float* bcos_w = (const float*)d_in[3];
    const float* gamma  = (const float*)d_in[4];
    const float* beta   = (const float*)d_in[5];
    float*       y      = (float*)d_out;

    // workspace layout
    float* h       = (float*)d_ws;                          // N*64 f
    float* inv_hn  = h + (size_t)N_NODES * HID;             // N*4 f
    int*   deg     = (int*)(inv_hn + (size_t)N_NODES * HEADS); // N i
    int*   cnt     = deg + N_NODES;                         // 8 i (sync counters)
    int*   partial = cnt + 8;                               // 64 i
    int*   offsets = partial + 64;                          // N+1 i
    int*   cursor  = offsets + N_NODES + 1;                 // N i
    int*   csr_col = cursor + N_NODES;                      // E i

    // grid = #CUs so all blocks are co-resident (grid_sync requirement)
    int dev = 0, ncu = 256;
    hipGetDevice(&dev);
    hipDeviceGetAttribute(&ncu, hipDeviceAttributeMultiprocessorCount, dev);
    if (ncu <= 0 || ncu > 256) ncu = 256;
    if (ncu < NCHUNK) ncu = NCHUNK;

    // zero deg + sync counters (one memset node)
    hipMemsetAsync(deg, 0, (N_NODES + 8) * sizeof(int), stream);

    mega_kernel<<<ncu, 1024, 0, stream>>>(x, ei, lin_w, bcos_w, gamma, beta, y,
                                          h, inv_hn, deg, cnt, partial,
                                          offsets, cursor, csr_col);
}

// Round 10
// 185.551 us; speedup vs baseline: 4.6671x; 4.6671x over previous
//
#include <hip/hip_runtime.h>
#include <math.h>

#define N_NODES 50000
#define IN_CH   128
#define HEADS   4
#define HID     64
#define NEDGE   800000
#define EPS     1e-6f
#define LN_EPS  1e-5f

// ---- cross-lane reduce helpers --------------------------------------
#define DPP_ADD_F(p, ctrl) \
    p += __int_as_float(__builtin_amdgcn_update_dpp(0, __float_as_int(p), ctrl, 0xF, 0xF, true))
// 16-lane butterfly: xor {1,2,7,15}
#define REDUCE16_DPP(p) { DPP_ADD_F(p,0xB1); DPP_ADD_F(p,0x4E); \
                          DPP_ADD_F(p,0x141); DPP_ADD_F(p,0x140); }
#define REDUCE16(p) { p += __shfl_xor(p,1); p += __shfl_xor(p,2); \
                      p += __shfl_xor(p,4); p += __shfl_xor(p,8); }
#define REDUCE64(p) { REDUCE16_DPP(p); p += __shfl_xor(p,16); p += __shfl_xor(p,32); }
#define REDUCE64I(p) { p += __shfl_xor(p,1); p += __shfl_xor(p,2); \
                       p += __shfl_xor(p,4); p += __shfl_xor(p,8); \
                       p += __shfl_xor(p,16); p += __shfl_xor(p,32); }

// ---------------- kernel B1: per-1024-chunk partial sums + inv_w -----
__global__ __launch_bounds__(1024) void partial_kernel(const int* __restrict__ deg,
                                                       int* __restrict__ partial,
                                                       const float* __restrict__ bcos_w,
                                                       float* __restrict__ inv_w) {
    __shared__ int wsum[16];
    int tid = threadIdx.x, lane = tid & 63, w = tid >> 6;
    int i = blockIdx.x * 1024 + tid;
    int v = (i < N_NODES) ? deg[i] : 0;
    REDUCE64I(v);
    if (lane == 0) wsum[w] = v;
    __syncthreads();
    if (w == 0) {
        int t = (lane < 16) ? wsum[lane] : 0;
        REDUCE16(t);
        if (lane == 0) partial[blockIdx.x] = t;
    }
    if (blockIdx.x == 0 && w == 15) {      // fused: bcos_w row inverse norms
        int j = lane;
        const float4* w4 = (const float4*)bcos_w;
        float ss = 0.f;
#pragma unroll
        for (int k4 = 0; k4 < HID / 4; ++k4) {
            float4 q = w4[j * (HID / 4) + k4];
            ss += q.x * q.x + q.y * q.y + q.z * q.z + q.w * q.w;
        }
        inv_w[j] = 1.0f / fmaxf(sqrtf(ss), 1e-12f);
    }
}

// ---------------- kernel B2: block-scan -> offsets + cursor ----------
__global__ __launch_bounds__(1024) void offsets_kernel(const int* __restrict__ deg,
                                                       const int* __restrict__ partial,
                                                       int* __restrict__ offsets,
                                                       int* __restrict__ cursor) {
    __shared__ int wsum[16];
    __shared__ int bbase_s;
    int tid = threadIdx.x, lane = tid & 63, w = tid >> 6;
    int b = blockIdx.x;

    if (tid < 64) {
        int v = (lane < b) ? partial[lane] : 0;
        REDUCE64I(v);
        if (lane == 0) bbase_s = v;
    }

    int i = b * 1024 + tid;
    int val = (i < N_NODES) ? deg[i] : 0;
    int s = val;
#pragma unroll
    for (int off = 1; off < 64; off <<= 1) {
        int t = __shfl_up(s, off);
        if (lane >= off) s += t;
    }
    if (lane == 63) wsum[w] = s;
    __syncthreads();
    if (w == 0 && lane < 16) {
        int t = wsum[lane];
#pragma unroll
        for (int off = 1; off < 16; off <<= 1) {
            int u = __shfl_up(t, off);
            if (lane >= off) t += u;
        }
        wsum[lane] = t;
    }
    __syncthreads();
    int incl = bbase_s + ((w == 0) ? 0 : wsum[w - 1]) + s;
    if (i < N_NODES) {
        offsets[i] = incl - val;
        cursor[i]  = incl - val;
    }
    if (b == gridDim.x - 1 && tid == 1023) offsets[N_NODES] = incl;
}

// ---------------- kernel C: CSR fill (int4) ---------------------------
__global__ __launch_bounds__(256) void fill_kernel(const int* __restrict__ ei,
                                                   int* __restrict__ cursor,
                                                   int* __restrict__ csr_col) {
    int t = blockIdx.x * 256 + threadIdx.x;
    if (t < NEDGE / 4) {
        int4 r = ((const int4*)ei)[t];
        int4 c = ((const int4*)(ei + NEDGE))[t];
        csr_col[atomicAdd(&cursor[r.x], 1)] = c.x;
        csr_col[atomicAdd(&cursor[r.y], 1)] = c.y;
        csr_col[atomicAdd(&cursor[r.z], 1)] = c.z;
        csr_col[atomicAdd(&cursor[r.w], 1)] = c.w;
    }
}

// ---------------- kernel D: hist (fire-and-forget) + h GEMM ----------
__global__ __launch_bounds__(256) void h_kernel(const float* __restrict__ x,
                                                const float* __restrict__ lin_w,
                                                float* __restrict__ h,
                                                float* __restrict__ inv_hn,
                                                const int* __restrict__ ei,
                                                int* __restrict__ deg) {
    int t = blockIdx.x * 256 + threadIdx.x;
    if (t < NEDGE / 4) {
        int4 r = ((const int4*)ei)[t];
        atomicAdd(&deg[r.x], 1);
        atomicAdd(&deg[r.y], 1);
        atomicAdd(&deg[r.z], 1);
        atomicAdd(&deg[r.w], 1);
    }

    __shared__ float4 wt[32 * 65];               // [k4][c], lane-contiguous
    const float4* w4g = (const float4*)lin_w;    // [c][k4]
    for (int i = threadIdx.x; i < HID * (IN_CH / 4); i += 256) {
        int c = i >> 5, k4 = i & 31;
        wt[k4 * 65 + c] = w4g[i];
    }
    __syncthreads();

    int wave = threadIdx.x >> 6;
    int lane = threadIdx.x & 63;
    const float4* xp = (const float4*)x;

    for (int g = blockIdx.x; g < N_NODES / 16; g += gridDim.x) {
        int n0 = __builtin_amdgcn_readfirstlane(g * 16 + wave * 4);

        float a0 = 0.f, a1 = 0.f, a2 = 0.f, a3 = 0.f;
#pragma unroll 2
        for (int k4 = 0; k4 < IN_CH / 4; ++k4) {
            float4 wv = wt[k4 * 65 + lane];
            float4 x0 = xp[(n0 + 0) * 32 + k4];  // uniform -> s_load
            float4 x1 = xp[(n0 + 1) * 32 + k4];
            float4 x2 = xp[(n0 + 2) * 32 + k4];
            float4 x3 = xp[(n0 + 3) * 32 + k4];
            a0 += wv.x * x0.x + wv.y * x0.y + wv.z * x0.z + wv.w * x0.w;
            a1 += wv.x * x1.x + wv.y * x1.y + wv.z * x1.z + wv.w * x1.w;
            a2 += wv.x * x2.x + wv.y * x2.y + wv.z * x2.z + wv.w * x2.w;
            a3 += wv.x * x3.x + wv.y * x3.y + wv.z * x3.z + wv.w * x3.w;
        }

        float accs[4] = {a0, a1, a2, a3};
#pragma unroll
        for (int j = 0; j < 4; ++j) {
            int node = n0 + j;
            h[node * HID + lane] = accs[j];
            float ss = accs[j] * accs[j];
            REDUCE16_DPP(ss);
            if ((lane & 15) == 0)
                inv_hn[node * HEADS + (lane >> 4)] = 1.0f / fmaxf(sqrtf(ss), 1e-12f);
        }
    }
}

// ---------------- kernel E: gather (ILP-16) + bcos + layernorm -------
// __launch_bounds__(256,4): 128-VGPR budget -> ILP-16 without spill,
// 4 blocks/CU (16 waves) occupancy.
__global__ __launch_bounds__(256, 4) void gather_final(const int* __restrict__ offsets,
                                                       const int* __restrict__ csr_col,
                                                       const float* __restrict__ h,
                                                       const float* __restrict__ inv_hn,
                                                       const float* __restrict__ bcos_w,
                                                       const float* __restrict__ inv_w_g,
                                                       const float* __restrict__ gamma,
                                                       const float* __restrict__ beta,
                                                       float* __restrict__ y) {
    __shared__ float4 wt4[16][65];               // padded staging
    __shared__ float rowbuf[4][HID];
    __shared__ float ivw[HID], gm[HID], bt[HID];

    for (int i = threadIdx.x; i < HID * (HID / 4); i += 256) {
        int j = i >> 4, k4 = i & 15;
        wt4[k4][j] = ((const float4*)bcos_w)[i];
    }
    if (threadIdx.x < HID) {
        ivw[threadIdx.x] = inv_w_g[threadIdx.x];
        gm[threadIdx.x]  = gamma[threadIdx.x];
        bt[threadIdx.x]  = beta[threadIdx.x];
    }
    __syncthreads();

    int grp  = threadIdx.x >> 6;
    int lane = threadIdx.x & 63;
    int head = lane >> 4;

    for (int g = blockIdx.x; g < N_NODES / 4; g += gridDim.x) {
        int node = g * 4 + grp;
        float hr  = h[node * HID + lane];
        float ihr = inv_hn[node * HEADS + head];
        float hrs = hr * ihr;
        int start = __builtin_amdgcn_readfirstlane(offsets[node]);
        int end   = __builtin_amdgcn_readfirstlane(offsets[node + 1]);

        float ac0 = 0.f, ac1 = 0.f, ac2 = 0.f, ac3 = 0.f;
        int b = start;
#pragma unroll 1
        for (; b + 16 <= end; b += 16) {
            int cc[16];
#pragma unroll
            for (int j = 0; j < 16; ++j) cc[j] = csr_col[b + j];      // s_loads
            float hh[16];
#pragma unroll
            for (int j = 0; j < 16; ++j) hh[j] = h[cc[j] * HID + lane];
            float ii[16];
#pragma unroll
            for (int j = 0; j < 16; ++j) ii[j] = inv_hn[cc[j] * HEADS + head];
#pragma unroll
            for (int j = 0; j < 16; ++j) {
                float p = hh[j] * hrs;
                REDUCE16_DPP(p);
                float s = fminf(fmaxf(p * ii[j], EPS), 1.0f);   // B_EXP=2
                if ((j & 3) == 0)      ac0 = fmaf(hh[j], s, ac0);
                else if ((j & 3) == 1) ac1 = fmaf(hh[j], s, ac1);
                else if ((j & 3) == 2) ac2 = fmaf(hh[j], s, ac2);
                else                   ac3 = fmaf(hh[j], s, ac3);
            }
        }
        int rem = end - b;
        if (rem > 0) {                       // masked 16-wide tail (uniform idx)
            int cc[16];
#pragma unroll
            for (int j = 0; j < 16; ++j) cc[j] = csr_col[b + ((j < rem) ? j : rem - 1)];
            float hh[16];
#pragma unroll
            for (int j = 0; j < 16; ++j) hh[j] = h[cc[j] * HID + lane];
            float ii[16];
#pragma unroll
            for (int j = 0; j < 16; ++j) ii[j] = inv_hn[cc[j] * HEADS + head];
#pragma unroll
            for (int j = 0; j < 16; ++j) {
                float p = hh[j] * hrs;
                REDUCE16_DPP(p);
                float s = fminf(fmaxf(p * ii[j], EPS), 1.0f);
                s = (j < rem) ? s : 0.0f;
                if (j & 1) ac1 = fmaf(hh[j], s, ac1);
                else       ac0 = fmaf(hh[j], s, ac0);
            }
        }
        float acc = (ac0 + ac1) + (ac2 + ac3);

        // ---- fused epilogue: bcos linear + layernorm ----
        rowbuf[grp][lane] = acc;             // wave-private
        float ss = acc * acc;
        REDUCE64(ss);
        float inv_no = 1.0f / fmaxf(sqrtf(ss), 1e-12f);

        const float4* rb4 = (const float4*)rowbuf[grp];
        float lin = 0.f;
#pragma unroll
        for (int k4 = 0; k4 < 16; ++k4) {
            float4 a  = rb4[k4];             // broadcast read
            float4 wv = wt4[k4][lane];       // contiguous b128
            lin += a.x * wv.x + a.y * wv.y + a.z * wv.z + a.w * wv.w;
        }

        float c2v = lin * inv_no * ivw[lane];
        c2v = fminf(fmaxf(c2v, EPS), 1.0f);
        float ob = lin * c2v;                // B_EXP=2 -> cos2**1

        float mu = ob;
        REDUCE64(mu);
        mu *= (1.0f / 64.0f);
        float d = ob - mu;
        float var = d * d;
        REDUCE64(var);
        var *= (1.0f / 64.0f);
        float r = rsqrtf(var + LN_EPS);
        y[node * HID + lane] = d * r * gm[lane] + bt[lane];
    }
}

// ---------------------------------------------------------------------
extern "C" void kernel_launch(void* const* d_in, const int* in_sizes, int n_in,
                              void* d_out, int out_size, void* d_ws, size_t ws_size,
                              hipStream_t stream) {
    const float* x      = (const float*)d_in[0];
    const int*   ei     = (const int*)d_in[1];
    const float* lin_w  = (const float*)d_in[2];
    const float* bcos_w = (const float*)d_in[3];
    const float* gamma  = (const float*)d_in[4];
    const float* beta   = (const float*)d_in[5];
    float*       y      = (float*)d_out;

    // workspace layout
    float* h       = (float*)d_ws;                          // N*64 f
    float* inv_hn  = h + (size_t)N_NODES * HID;             // N*4 f
    float* inv_w   = inv_hn + (size_t)N_NODES * HEADS;      // 64 f
    int*   deg     = (int*)(inv_w + HID);                   // N i
    int*   partial = deg + N_NODES;                         // 64 i
    int*   offsets = partial + 64;                          // N+1 i
    int*   cursor  = offsets + N_NODES + 1;                 // N i
    int*   csr_col = cursor + N_NODES;                      // E i

    const int SCAN_BLOCKS = (N_NODES + 1023) / 1024;        // 49

    hipMemsetAsync(deg, 0, N_NODES * sizeof(int), stream);

    h_kernel<<<1024, 256, 0, stream>>>(x, lin_w, h, inv_hn, ei, deg);

    partial_kernel<<<SCAN_BLOCKS, 1024, 0, stream>>>(deg, partial, bcos_w, inv_w);

    offsets_kernel<<<SCAN_BLOCKS, 1024, 0, stream>>>(deg, partial, offsets, cursor);

    fill_kernel<<<(NEDGE / 4 + 255) / 256, 256, 0, stream>>>(ei, cursor, csr_col);

    gather_final<<<2048, 256, 0, stream>>>(offsets, csr_col, h, inv_hn,
                                           bcos_w, inv_w, gamma, beta, y);
}